// Round 1
// 1129.507 us; speedup vs baseline: 1.0281x; 1.0281x over previous
//
#include <hip/hip_runtime.h>
#include <math.h>

#define NN 256
#define TT 1024
#define KK 1000
#define DD 64
#define EPS 1e-8f

// Output layout (flat floats in d_out):
//   [0,256)      ll_N
//   [256]        time_loglik (scalar)
//   [257,513)    time_loglik_NT
//   [513, ...)   type_emb (N*T*D = 16777216)
#define OUT_LL    0
#define OUT_SCAL  256
#define OUT_TNT   257
#define OUT_EMB   513

// ---------------------------------------------------------------------------
// Block reduction helper: 256 threads = 4 waves of 64.
// Reduction order identical to previous (verified absmax == 0.0) version.
// ---------------------------------------------------------------------------
__device__ __forceinline__ float block_sum(float v, float* s4) {
    #pragma unroll
    for (int off = 32; off > 0; off >>= 1)
        v += __shfl_down(v, off, 64);
    int lane = threadIdx.x & 63;
    int w    = threadIdx.x >> 6;
    if (lane == 0) s4[w] = v;
    __syncthreads();
    return s4[0] + s4[1] + s4[2] + s4[3];        // valid in all threads
}

// ---------------------------------------------------------------------------
// Fused kernel:
//   blocks [0,256):       per-trajectory reductions (latency-bound gathers)
//   blocks [256, 65792):  type_emb fill (write-BW-bound)
// Row blocks are FIRST in dispatch order so their ~900-cycle HBM gather
// latency hides under the emb write flood; previously they ran alone at
// 1 block/CU (1 wave/SIMD) with nothing to overlap with.
// Non-temporal hints on the two streaming, never-reused streams
// (prob_event gather lines, emb stores) keep L2 for type_table/event_types.
// ---------------------------------------------------------------------------
__global__ __launch_bounds__(256) void fused_kernel(
    const int* __restrict__ event_types,
    const float* __restrict__ prob_event,
    const float* __restrict__ intensities,
    const float* __restrict__ Lambda,
    const float* __restrict__ input_mask,
    const float* __restrict__ type_table,
    float* __restrict__ out)
{
    __shared__ float s_a[4];
    __shared__ float s_b[4];
    int b = blockIdx.x;
    if (b < NN) {
        // ---- per-trajectory reductions, i = b ----
        int i = b;
        float ev = 0.f, tm = 0.f;
        #pragma unroll
        for (int k = 0; k < TT / 256; ++k) {
            int j  = k * 256 + threadIdx.x;
            int ij = i * TT + j;
            float m = input_mask[ij];
            int   e = event_types[ij];
            // 4B gather, ~random in K over a 1 GiB buffer: always misses,
            // lines never reused -> non-temporal.
            float p = __builtin_nontemporal_load(&prob_event[(size_t)ij * KK + e]);
            ev += logf(p + EPS) * m;
            tm += logf(intensities[ij] + EPS) * m;
        }
        float ev_tot = block_sum(ev, s_a);
        float tm_tot = block_sum(tm, s_b);
        if (threadIdx.x == 0) {
            float tnt = tm_tot - Lambda[i];
            out[OUT_TNT + i] = tnt;
            out[OUT_LL  + i] = tnt + ev_tot;
        }
    } else {
        // ---- type_emb[i,j,d] = type_table[event_types[i,j], d] ----
        // Threads 0..63 of a wave share one (i,j) row (D == 64 == wave size):
        // table row read coalesced (256B/wave), emb write coalesced and
        // line-complete (256B/wave). Scalar stores: emb base only 4B-aligned.
        int idx = (b - NN) * 256 + threadIdx.x;   // < N*T*D = 16777216
        int row = idx >> 6;                        // (i*T + j)
        int d   = idx & 63;
        int e   = event_types[row];                // broadcast within wave (L1)
        __builtin_nontemporal_store(type_table[e * DD + d], &out[OUT_EMB + idx]);
    }
}

// ---------------------------------------------------------------------------
// Final scalar: time_loglik = sum_i ll_N[i]. Separate launch so it sees all
// 256 row-block results; keeps the exact deterministic reduction order.
// ---------------------------------------------------------------------------
__global__ __launch_bounds__(256) void sum_kernel(float* __restrict__ out)
{
    __shared__ float s_a[4];
    float v = out[OUT_LL + threadIdx.x];
    float tot = block_sum(v, s_a);
    if (threadIdx.x == 0) out[OUT_SCAL] = tot;
}

extern "C" void kernel_launch(void* const* d_in, const int* in_sizes, int n_in,
                              void* d_out, int out_size, void* d_ws, size_t ws_size,
                              hipStream_t stream) {
    const int*   event_types = (const int*)  d_in[0];   // (N,T) int32
    const float* prob_event  = (const float*)d_in[1];   // (N,T,K) f32
    const float* intensities = (const float*)d_in[2];   // (N,T) f32
    const float* Lambda      = (const float*)d_in[3];   // (N,) f32
    const float* input_mask  = (const float*)d_in[4];   // (N,T) f32
    const float* type_table  = (const float*)d_in[5];   // (K,D) f32
    float* out = (float*)d_out;

    fused_kernel<<<NN + (NN * TT * DD) / 256, 256, 0, stream>>>(
        event_types, prob_event, intensities, Lambda, input_mask, type_table, out);
    sum_kernel<<<1, 256, 0, stream>>>(out);
}